// Round 4
// baseline (706.497 us; speedup 1.0000x reference)
//
#include <hip/hip_runtime.h>

// SpectralLayer reduction (algebra verified against the reference):
//   layer = I + W, W nonzero only rows [512,1024) x cols [0,512); W[n][k] = base[512+n][k]
//   d_i = 1 (i<512);  d_{512+n} = v^2 - v + 1 with v = diag value (read from inputs)
//   out[:, :512]  = data[:, :512]                         (exact pass-through, no relu)
//   out[:, 512+n] = relu( d_n * data[:,512+n] + (1-d_n) * t_n ),  t = data[:, :512] @ W^T
//
// Round 4: dtype-self-detecting, pure-VALU fp32 GEMM (no MFMA, no __bf16, no
// builtins) — maximum build safety. First 4 bytes of `eye`: 0x3F800000 => fp32
// buffers; 0x00003F80 => bf16 buffers. Wave-uniform branch picks the IO path.

#define DIMW   1024
#define HALFD  512
#define BMT    128
#define BNT    128
#define BKT    32
#define LPAD   36    // LDS row stride (floats): 16B-aligned rows, conflict-free reads

__device__ __forceinline__ float bf2f(unsigned short u) {
    union { unsigned int i; float f; } c;
    c.i = ((unsigned int)u) << 16;
    return c.f;
}
__device__ __forceinline__ unsigned short f2bf(float x) {
    union { float f; unsigned int i; } c;
    c.f = x;
    unsigned int r = c.i + 0x7FFFu + ((c.i >> 16) & 1u);  // round-nearest-even
    return (unsigned short)(r >> 16);
}

template <bool F32>
__device__ __forceinline__ float ldg(const void* p, size_t i) {
    if constexpr (F32) {
        return ((const float*)p)[i];
    } else {
        return bf2f(((const unsigned short*)p)[i]);
    }
}

template <bool F32>
__device__ void body(const void* data, const void* wsrc, const void* td,
                     const void* tdm, const void* ud, void* out,
                     float* As, float* Bs, float* dsh)
{
    const int tid = (int)threadIdx.x;
    const int tx  = tid & 15;          // col lane group
    const int ty  = tid >> 4;          // row lane group
    const int rowBase = (int)blockIdx.x * BMT;
    const int colBase = (int)blockIdx.y * BNT;   // n in [0,512)

    // d[n] for this block's 128 output columns (diag entries at [512+n][512+n])
    if (tid < BNT) {
        int j = HALFD + colBase + tid;
        size_t fi = (size_t)j * DIMW + j;
        dsh[tid] = ldg<F32>(td, fi) * ldg<F32>(tdm, fi) + ldg<F32>(ud, fi);
    }

    // Fused pass-through copy: out[rowBase..+128, colBase..+128) = data[same]
    if constexpr (F32) {
        const float4* src = (const float4*)data;   // 256 float4 per row
        float4*       dst = (float4*)out;
        #pragma unroll
        for (int p = 0; p < 16; ++p) {
            int c  = p * 256 + tid;                // 4096 chunks: 128 rows x 32
            int r  = c >> 5;
            int cc = c & 31;
            size_t off = (size_t)(rowBase + r) * (DIMW / 4) + (colBase >> 2) + cc;
            dst[off] = src[off];
        }
    } else {
        const int4* src = (const int4*)data;       // 8 bf16 per int4; 128 per row
        int4*       dst = (int4*)out;
        #pragma unroll
        for (int p = 0; p < 8; ++p) {
            int c  = p * 256 + tid;                // 2048 chunks: 128 rows x 16
            int r  = c >> 4;
            int cc = c & 15;
            size_t off = (size_t)(rowBase + r) * (DIMW / 8) + (colBase >> 3) + cc;
            dst[off] = src[off];
        }
    }

    float acc[8][8];
    #pragma unroll
    for (int i = 0; i < 8; ++i) {
        #pragma unroll
        for (int j = 0; j < 8; ++j) {
            acc[i][j] = 0.0f;
        }
    }

    for (int k0 = 0; k0 < HALFD; k0 += BKT) {
        __syncthreads();   // previous tile fully consumed before overwrite

        // Stage A (data rows) and B (W rows): 128 rows x 32 k, fp32 in LDS.
        // chunk = 4 elements; 1024 chunks; each thread stages 4 per matrix.
        #pragma unroll
        for (int p = 0; p < 4; ++p) {
            int c  = p * 256 + tid;
            int r  = c >> 3;
            int kc = (c & 7) * 4;
            if constexpr (F32) {
                const float* ap = (const float*)data + (size_t)(rowBase + r) * DIMW + k0 + kc;
                const float* bp = (const float*)wsrc + (size_t)(HALFD + colBase + r) * DIMW + k0 + kc;
                float4 av = *(const float4*)ap;
                float4 bv = *(const float4*)bp;
                As[r * LPAD + kc + 0] = av.x;
                As[r * LPAD + kc + 1] = av.y;
                As[r * LPAD + kc + 2] = av.z;
                As[r * LPAD + kc + 3] = av.w;
                Bs[r * LPAD + kc + 0] = bv.x;
                Bs[r * LPAD + kc + 1] = bv.y;
                Bs[r * LPAD + kc + 2] = bv.z;
                Bs[r * LPAD + kc + 3] = bv.w;
            } else {
                const unsigned short* ap = (const unsigned short*)data + (size_t)(rowBase + r) * DIMW + k0 + kc;
                const unsigned short* bp = (const unsigned short*)wsrc + (size_t)(HALFD + colBase + r) * DIMW + k0 + kc;
                uint2 av = *(const uint2*)ap;      // 4 bf16 (8 bytes, aligned)
                uint2 bv = *(const uint2*)bp;
                As[r * LPAD + kc + 0] = bf2f((unsigned short)(av.x & 0xFFFFu));
                As[r * LPAD + kc + 1] = bf2f((unsigned short)(av.x >> 16));
                As[r * LPAD + kc + 2] = bf2f((unsigned short)(av.y & 0xFFFFu));
                As[r * LPAD + kc + 3] = bf2f((unsigned short)(av.y >> 16));
                Bs[r * LPAD + kc + 0] = bf2f((unsigned short)(bv.x & 0xFFFFu));
                Bs[r * LPAD + kc + 1] = bf2f((unsigned short)(bv.x >> 16));
                Bs[r * LPAD + kc + 2] = bf2f((unsigned short)(bv.y & 0xFFFFu));
                Bs[r * LPAD + kc + 3] = bf2f((unsigned short)(bv.y >> 16));
            }
        }
        __syncthreads();

        // Compute: thread owns rows {ty+16i}, cols {tx+16j}.
        // a-reads broadcast over tx (free); b-reads stride 36 floats over tx
        // -> bank stride 4, 2-way aliasing (free per m136).
        #pragma unroll
        for (int kk = 0; kk < BKT; kk += 4) {
            float4 a4[8];
            #pragma unroll
            for (int i = 0; i < 8; ++i) {
                a4[i] = *(const float4*)&As[(ty + 16 * i) * LPAD + kk];
            }
            #pragma unroll
            for (int j = 0; j < 8; ++j) {
                float4 b4 = *(const float4*)&Bs[(tx + 16 * j) * LPAD + kk];
                #pragma unroll
                for (int i = 0; i < 8; ++i) {
                    acc[i][j] += a4[i].x * b4.x;
                    acc[i][j] += a4[i].y * b4.y;
                    acc[i][j] += a4[i].z * b4.z;
                    acc[i][j] += a4[i].w * b4.w;
                }
            }
        }
    }

    // Epilogue: out[row, 512+n] = relu(d*u1 + (1-d)*t). Lane tx consecutive in
    // n -> coalesced dword accesses.
    #pragma unroll
    for (int i = 0; i < 8; ++i) {
        int row = rowBase + ty + 16 * i;
        #pragma unroll
        for (int j = 0; j < 8; ++j) {
            int nloc = tx + 16 * j;
            float dv = dsh[nloc];
            int col  = HALFD + colBase + nloc;
            size_t gi = (size_t)row * DIMW + col;
            float u1 = ldg<F32>(data, gi);
            float v  = dv * u1 + (1.0f - dv) * acc[i][j];
            v = fmaxf(v, 0.0f);
            if constexpr (F32) {
                ((float*)out)[gi] = v;
            } else {
                ((unsigned short*)out)[gi] = f2bf(v);
            }
        }
    }
}

__global__ __launch_bounds__(256) void spectral_kernel(
    const void* data, const void* wsrc, const void* td, const void* tdm,
    const void* ud, const void* eye, void* out)
{
    __shared__ float As[BMT * LPAD];
    __shared__ float Bs[BNT * LPAD];
    __shared__ float dsh[BNT];

    // dtype probe: fp32 eye[0] = 1.0f -> dword 0x3F800000;
    // bf16 eye[0:2] = {1.0bf16, 0.0} -> dword 0x00003F80. Grid-uniform branch.
    unsigned int probe = *(const unsigned int*)eye;
    if (probe == 0x3F800000u) {
        body<true>(data, wsrc, td, tdm, ud, out, As, Bs, dsh);
    } else {
        body<false>(data, wsrc, td, tdm, ud, out, As, Bs, dsh);
    }
}

extern "C" void kernel_launch(void* const* d_in, const int* in_sizes, int n_in,
                              void* d_out, int out_size, void* d_ws, size_t ws_size,
                              hipStream_t stream) {
    // setup_inputs order: 0 data, 1 base, 2 base_mask, 3 eye, 4 trainable_diag,
    //                     5 trainable_diag_mask, 6 untrainable_diag, 7 mask1, 8 mask2
    const void* data = d_in[0];
    const void* base = d_in[1];
    const void* eye  = d_in[3];
    const void* td   = d_in[4];
    const void* tdm  = d_in[5];
    const void* ud   = d_in[6];

    dim3 grid(32768 / BMT, HALFD / BNT);   // 256 x 4 = 1024 blocks
    dim3 block(256, 1, 1);
    spectral_kernel<<<grid, block, 0, stream>>>(data, base, td, tdm, ud, eye, d_out);
}

// Round 5
// 298.727 us; speedup vs baseline: 2.3650x; 2.3650x over previous
//
#include <hip/hip_runtime.h>

// SpectralLayer reduction (algebra verified; fp32 buffers confirmed round 4):
//   out[:, :512]  = data[:, :512]                        (exact pass-through)
//   out[:, 512+n] = relu( d_n*data[:,512+n] + (1-d_n)*t_n ),
//       t = data[:, :512] @ W^T,  W[n][k] = base[512+n][k],  d = v^2 - v + 1
// Round 5: round-4 skeleton (proven correct) + bf16 MFMA inner loop via INLINE
// ASM (v_mfma_f32_16x16x32_bf16) — the __builtin_amdgcn_mfma_* path failed to
// build in rounds 1-3 with both known signatures. fp32->bf16 RNE in staging.

typedef float f32x4 __attribute__((ext_vector_type(4)));
typedef int   i32x4 __attribute__((ext_vector_type(4)));

#define DIMW   1024
#define HALFD  512
#define BM     128
#define BN     128
#define BK     32

__device__ __forceinline__ unsigned short f2bf(float x) {
    union { float f; unsigned int i; } c;
    c.f = x;
    unsigned int r = c.i + 0x7FFFu + ((c.i >> 16) & 1u);  // round-nearest-even
    return (unsigned short)(r >> 16);
}
__device__ __forceinline__ unsigned int pack2(float a, float b) {
    return (unsigned int)f2bf(a) | ((unsigned int)f2bf(b) << 16);
}

// D(f32x4) += A(8 bf16 in 4 VGPRs) * B(8 bf16 in 4 VGPRs); C tied to D.
__device__ __forceinline__ void mfma_16x16x32_bf16(f32x4& d, const i32x4& a, const i32x4& b) {
    asm volatile("v_mfma_f32_16x16x32_bf16 %0, %1, %2, %0"
                 : "+v"(d)
                 : "v"(a), "v"(b));
}
// Hazard fence: VALU may not read an MFMA result for ~8 cycles; tie the nops to
// the acc registers so the epilogue reads cannot be scheduled before them.
__device__ __forceinline__ void acc_fence(f32x4& d) {
    asm volatile("s_nop 7\n\ts_nop 7" : "+v"(d));
}

__global__ __launch_bounds__(256) void spectral_kernel(
    const float* __restrict__ data,
    const float* __restrict__ wsrc,   // base: W at rows [512,1024), cols [0,512)
    const float* __restrict__ td,
    const float* __restrict__ tdm,
    const float* __restrict__ ud,
    float* __restrict__ out)
{
    __shared__ unsigned short As[BM * BK];   // [128][32] bf16, k-contiguous (m97 layout)
    __shared__ unsigned short Bs[BN * BK];
    __shared__ float dsh[BN];

    const int tid    = (int)threadIdx.x;
    const int lane   = tid & 63;
    const int wave   = tid >> 6;
    const int lane16 = lane & 15;
    const int quad   = lane >> 4;
    const int wm     = wave >> 1;            // 2x2 wave grid, 64x64 per wave
    const int wn     = wave & 1;
    const int rowBase = (int)blockIdx.x * BM;
    const int colBase = (int)blockIdx.y * BN;   // n in [0,512)

    // d[n] for this block's 128 output columns (diag entries at [512+n][512+n])
    if (tid < BN) {
        int j = HALFD + colBase + tid;
        size_t fi = (size_t)j * DIMW + j;
        dsh[tid] = td[fi] * tdm[fi] + ud[fi];
    }

    // Fused pass-through copy: out[rowBase..+128, colBase..+128) = data[same]
    {
        const float4* src = (const float4*)data;   // 256 float4 per row
        float4*       dst = (float4*)out;
        #pragma unroll
        for (int p = 0; p < 16; ++p) {
            int c  = p * 256 + tid;                // 4096 chunks: 128 rows x 32
            int r  = c >> 5;
            int cc = c & 31;
            size_t off = (size_t)(rowBase + r) * (DIMW / 4) + (colBase >> 2) + cc;
            dst[off] = src[off];
        }
    }

    f32x4 acc[4][4];
    #pragma unroll
    for (int mi = 0; mi < 4; ++mi)
        #pragma unroll
        for (int ni = 0; ni < 4; ++ni)
            acc[mi][ni] = (f32x4){0.f, 0.f, 0.f, 0.f};

    for (int k0 = 0; k0 < HALFD; k0 += BK) {
        // Load fp32 tiles into registers (before barrier, for overlap).
        float4 av[4], bv[4];
        #pragma unroll
        for (int p = 0; p < 4; ++p) {
            int c  = p * 256 + tid;                // 4-float chunk id, 0..1023
            int r  = c >> 3;
            int kc = (c & 7) * 4;
            av[p] = *(const float4*)(data + (size_t)(rowBase + r) * DIMW + k0 + kc);
            bv[p] = *(const float4*)(wsrc + (size_t)(HALFD + colBase + r) * DIMW + k0 + kc);
        }
        __syncthreads();                           // previous tile fully consumed
        #pragma unroll
        for (int p = 0; p < 4; ++p) {
            int c  = p * 256 + tid;
            int r  = c >> 3;
            int kc = (c & 7) * 4;
            uint2 ua, ub;
            ua.x = pack2(av[p].x, av[p].y);  ua.y = pack2(av[p].z, av[p].w);
            ub.x = pack2(bv[p].x, bv[p].y);  ub.y = pack2(bv[p].z, bv[p].w);
            *(uint2*)(As + r * BK + kc) = ua;      // byte off = 64r + 2kc, 8B-aligned
            *(uint2*)(Bs + r * BK + kc) = ub;
        }
        __syncthreads();

        // Fragments: A[m=lane16][k=quad*8+j], B[n=lane16][k=quad*8+j]  (m97 layout)
        i32x4 a[4], b[4];
        #pragma unroll
        for (int mi = 0; mi < 4; ++mi)
            a[mi] = *(const i32x4*)(As + (wm * 64 + mi * 16 + lane16) * BK + quad * 8);
        #pragma unroll
        for (int ni = 0; ni < 4; ++ni)
            b[ni] = *(const i32x4*)(Bs + (wn * 64 + ni * 16 + lane16) * BK + quad * 8);

        #pragma unroll
        for (int mi = 0; mi < 4; ++mi)
            #pragma unroll
            for (int ni = 0; ni < 4; ++ni)
                mfma_16x16x32_bf16(acc[mi][ni], a[mi], b[ni]);
    }

    #pragma unroll
    for (int mi = 0; mi < 4; ++mi)
        #pragma unroll
        for (int ni = 0; ni < 4; ++ni)
            acc_fence(acc[mi][ni]);

    // Epilogue. C/D layout: col(n) = lane&15, row(m) = quad*4 + reg. [m89 verified]
    #pragma unroll
    for (int mi = 0; mi < 4; ++mi) {
        int mBase = rowBase + wm * 64 + mi * 16 + quad * 4;
        #pragma unroll
        for (int ni = 0; ni < 4; ++ni) {
            int nloc = wn * 64 + ni * 16 + lane16;
            float dv = dsh[nloc];
            int col  = HALFD + colBase + nloc;
            #pragma unroll
            for (int r = 0; r < 4; ++r) {
                int row  = mBase + r;
                size_t gi = (size_t)row * DIMW + col;
                float u1 = data[gi];
                float v  = dv * u1 + (1.0f - dv) * acc[mi][ni][r];
                out[gi] = fmaxf(v, 0.0f);
            }
        }
    }
}

extern "C" void kernel_launch(void* const* d_in, const int* in_sizes, int n_in,
                              void* d_out, int out_size, void* d_ws, size_t ws_size,
                              hipStream_t stream) {
    // setup_inputs order: 0 data, 1 base, 2 base_mask, 3 eye, 4 trainable_diag,
    //                     5 trainable_diag_mask, 6 untrainable_diag, 7 mask1, 8 mask2
    const float* data = (const float*)d_in[0];
    const float* base = (const float*)d_in[1];
    const float* td   = (const float*)d_in[4];
    const float* tdm  = (const float*)d_in[5];
    const float* ud   = (const float*)d_in[6];
    float* out = (float*)d_out;

    dim3 grid(32768 / BM, HALFD / BN);   // 256 x 4 = 1024 blocks
    dim3 block(256, 1, 1);
    spectral_kernel<<<grid, block, 0, stream>>>(data, base, td, tdm, ud, out);
}